// Round 6
// baseline (332.051 us; speedup 1.0000x reference)
//
#include <hip/hip_runtime.h>
#include <hip/hip_fp16.h>
#include <hip/hip_cooperative_groups.h>

namespace cg = cooperative_groups;

#define TOKENS_ 8192
#define HIDDEN_ 4096
#define EPS_ 1e-6f
#define FP8MAX_ 448.0f

typedef float f32x4 __attribute__((ext_vector_type(4)));
typedef unsigned int u32x4 __attribute__((ext_vector_type(4)));

static constexpr size_t NELEM = (size_t)TOKENS_ * HIDDEN_;  // 33,554,432
// ws layout: [0..4) scale | [4K..4K+32K) bmax | [64K ...) fp16 buf (fallback)
static constexpr size_t WS_SCALE_OFF = 0;
static constexpr size_t WS_BMAX_OFF = 4096;
static constexpr size_t WS_H16_OFF = 65536;
static constexpr size_t WS_NEEDED_FB = WS_H16_OFF + NELEM * sizeof(unsigned short);

static __device__ inline unsigned int pack_half2(float a, float b) {
    __half2 h = __floats2half2_rn(a, b);
    return *reinterpret_cast<unsigned int*>(&h);
}
static __device__ inline float2 unpack_half2(unsigned int u) {
    return __half22float2(*reinterpret_cast<const __half2*>(&u));
}
static __device__ inline float clip1(float x, float invs) {
    return fminf(fmaxf(x * invs, -FP8MAX_), FP8MAX_);
}

// ---------------- cooperative single-pass kernel ----------------
// 1024 blocks x 256 thr (4 blocks/CU). Block owns 8 rows; thread holds
// 8 rows x 16 floats fp16-packed in pk[64] VGPRs across the grid sync.
// ALL pk[] indices are literal constants (macro-expanded rows) so the
// array stays in registers — R3's spill was runtime indexing (rule #20).
__global__ __launch_bounds__(256, 4) void k_coop(
    const float* __restrict__ hs, const float* __restrict__ w,
    float* __restrict__ q_out, float* __restrict__ scale_out,
    float* __restrict__ bmax_arr)
{
    const int tid = threadIdx.x;
    const int wave = tid >> 6;
    const int row0 = blockIdx.x * 8;
    const size_t S4 = NELEM / 4;  // shard stride in f32x4 units
    const f32x4* __restrict__ w4 = reinterpret_cast<const f32x4*>(w);

    unsigned int pk[64];
    float bmax = 0.f;
    __shared__ float red[32];  // [row][wave] — unique slot per row, 1 barrier/row

#define ROW_J(R, J, SV)                                                       \
    {                                                                         \
        f32x4 a = __builtin_nontemporal_load(&base[tid + J * 256]);           \
        f32x4 b = __builtin_nontemporal_load(&base[tid + J * 256 + S4]);      \
        f32x4 c = __builtin_nontemporal_load(&base[tid + J * 256 + 2 * S4]);  \
        f32x4 d = __builtin_nontemporal_load(&base[tid + J * 256 + 3 * S4]);  \
        SV = (a + b) + (c + d);                                               \
        ss += SV.x * SV.x + SV.y * SV.y + SV.z * SV.z + SV.w * SV.w;          \
    }

#define ROW_O(R, J, SV)                                                       \
    {                                                                         \
        f32x4 wv = w4[tid + J * 256];                                         \
        f32x4 o = SV * inv * wv;                                              \
        pk[R * 8 + J * 2]     = pack_half2(o.x, o.y);                         \
        pk[R * 8 + J * 2 + 1] = pack_half2(o.z, o.w);                         \
        bmax = fmaxf(bmax, fmaxf(fmaxf(fabsf(o.x), fabsf(o.y)),               \
                                 fmaxf(fabsf(o.z), fabsf(o.w))));             \
    }

#define DO_ROW(R)                                                             \
    {                                                                         \
        const f32x4* __restrict__ base =                                      \
            reinterpret_cast<const f32x4*>(hs) +                              \
            (size_t)(row0 + R) * (HIDDEN_ / 4);                               \
        f32x4 sv0, sv1, sv2, sv3;                                             \
        float ss = 0.f;                                                       \
        ROW_J(R, 0, sv0) ROW_J(R, 1, sv1) ROW_J(R, 2, sv2) ROW_J(R, 3, sv3)   \
        for (int off = 32; off > 0; off >>= 1)                                \
            ss += __shfl_down(ss, off, 64);                                   \
        if ((tid & 63) == 0) red[R * 4 + wave] = ss;                          \
        __syncthreads();                                                      \
        ss = red[R * 4 + 0] + red[R * 4 + 1] + red[R * 4 + 2] +               \
             red[R * 4 + 3];                                                  \
        const float inv = rsqrtf(ss * (1.0f / HIDDEN_) + EPS_);               \
        ROW_O(R, 0, sv0) ROW_O(R, 1, sv1) ROW_O(R, 2, sv2) ROW_O(R, 3, sv3)   \
    }

    DO_ROW(0) DO_ROW(1) DO_ROW(2) DO_ROW(3)
    DO_ROW(4) DO_ROW(5) DO_ROW(6) DO_ROW(7)

    // block max -> bmax_arr[block] (no atomics)
    for (int off = 32; off > 0; off >>= 1)
        bmax = fmaxf(bmax, __shfl_down(bmax, off, 64));
    if ((tid & 63) == 0) red[wave] = bmax;  // rows done with red[0..3] long ago
    __syncthreads();
    if (tid == 0) {
        bmax_arr[blockIdx.x] =
            fmaxf(fmaxf(red[0], red[1]), fmaxf(red[2], red[3]));
        __threadfence();
    }

    cg::this_grid().sync();

    // every block reduces bmax_arr[1024] (L2-resident, 4 KiB)
    f32x4 bv = reinterpret_cast<const f32x4*>(bmax_arr)[tid];
    float am = fmaxf(fmaxf(bv.x, bv.y), fmaxf(bv.z, bv.w));
    for (int off = 32; off > 0; off >>= 1)
        am = fmaxf(am, __shfl_down(am, off, 64));
    __syncthreads();  // all waves past their red[] reads above
    if ((tid & 63) == 0) red[wave] = am;
    __syncthreads();
    am = fmaxf(fmaxf(red[0], red[1]), fmaxf(red[2], red[3]));
    const float scale = fmaxf(am, 1e-12f) / FP8MAX_;
    const float invs = 1.0f / scale;
    if (blockIdx.x == 0 && tid == 0) scale_out[0] = scale;

#define ST_J(R, J)                                                            \
    {                                                                         \
        float2 f0 = unpack_half2(pk[R * 8 + J * 2]);                          \
        float2 f1 = unpack_half2(pk[R * 8 + J * 2 + 1]);                      \
        f32x4 o;                                                              \
        o.x = clip1(f0.x, invs);                                              \
        o.y = clip1(f0.y, invs);                                              \
        o.z = clip1(f1.x, invs);                                              \
        o.w = clip1(f1.y, invs);                                              \
        __builtin_nontemporal_store(o, &dst[tid + J * 256]);                  \
    }

#define ST_ROW(R)                                                             \
    {                                                                         \
        f32x4* __restrict__ dst = reinterpret_cast<f32x4*>(q_out) +           \
                                  (size_t)(row0 + R) * (HIDDEN_ / 4);         \
        ST_J(R, 0) ST_J(R, 1) ST_J(R, 2) ST_J(R, 3)                           \
    }

    ST_ROW(0) ST_ROW(1) ST_ROW(2) ST_ROW(3)
    ST_ROW(4) ST_ROW(5) ST_ROW(6) ST_ROW(7)
}

// ---------------- fallback: proven R5 three-kernel path ----------------

__global__ __launch_bounds__(256) void k_norm_h(
    const float* __restrict__ hs, const float* __restrict__ w,
    unsigned int* __restrict__ normed_h2, float* __restrict__ bmax_arr)
{
    const int row = blockIdx.x;
    const int tid = threadIdx.x;
    const size_t S4 = NELEM / 4;
    const f32x4* __restrict__ base =
        reinterpret_cast<const f32x4*>(hs) + (size_t)row * (HIDDEN_ / 4);
    const f32x4* __restrict__ w4 = reinterpret_cast<const f32x4*>(w);

    f32x4 sv[4];
    float ss = 0.f;
#pragma unroll
    for (int j = 0; j < 4; ++j) {
        const size_t idx = (size_t)tid + j * 256;
        f32x4 a = __builtin_nontemporal_load(&base[idx]);
        f32x4 b = __builtin_nontemporal_load(&base[idx + S4]);
        f32x4 c = __builtin_nontemporal_load(&base[idx + 2 * S4]);
        f32x4 d = __builtin_nontemporal_load(&base[idx + 3 * S4]);
        f32x4 s = (a + b) + (c + d);
        sv[j] = s;
        ss += s.x * s.x + s.y * s.y + s.z * s.z + s.w * s.w;
    }
    __shared__ float red[4];
#pragma unroll
    for (int off = 32; off > 0; off >>= 1) ss += __shfl_down(ss, off, 64);
    const int wave = tid >> 6;
    if ((tid & 63) == 0) red[wave] = ss;
    __syncthreads();
    ss = red[0] + red[1] + red[2] + red[3];
    const float inv = rsqrtf(ss * (1.0f / HIDDEN_) + EPS_);

    uint2* __restrict__ out =
        reinterpret_cast<uint2*>(normed_h2) + (size_t)row * (HIDDEN_ / 4);
    float am = 0.f;
#pragma unroll
    for (int j = 0; j < 4; ++j) {
        const size_t idx = (size_t)tid + j * 256;
        f32x4 wv = w4[idx];
        f32x4 o = sv[j] * inv * wv;
        uint2 p;
        p.x = pack_half2(o.x, o.y);
        p.y = pack_half2(o.z, o.w);
        out[idx] = p;
        am = fmaxf(am, fmaxf(fmaxf(fabsf(o.x), fabsf(o.y)),
                             fmaxf(fabsf(o.z), fabsf(o.w))));
    }
    __shared__ float redm[4];
#pragma unroll
    for (int off = 32; off > 0; off >>= 1)
        am = fmaxf(am, __shfl_down(am, off, 64));
    if ((tid & 63) == 0) redm[wave] = am;
    __syncthreads();
    if (tid == 0)
        bmax_arr[row] = fmaxf(fmaxf(redm[0], redm[1]), fmaxf(redm[2], redm[3]));
}

__global__ __launch_bounds__(256) void k_amax_scale(
    const float* __restrict__ bmax_arr, float* __restrict__ ws_scale,
    float* __restrict__ scale_out)
{
    const int tid = threadIdx.x;
    const f32x4* __restrict__ b4 = reinterpret_cast<const f32x4*>(bmax_arr);
    float am = 0.f;
#pragma unroll
    for (int j = 0; j < 8; ++j) {
        f32x4 v = b4[tid + j * 256];
        am = fmaxf(am, fmaxf(fmaxf(v.x, v.y), fmaxf(v.z, v.w)));
    }
    __shared__ float red[4];
#pragma unroll
    for (int off = 32; off > 0; off >>= 1)
        am = fmaxf(am, __shfl_down(am, off, 64));
    if ((tid & 63) == 0) red[tid >> 6] = am;
    __syncthreads();
    if (tid == 0) {
        am = fmaxf(fmaxf(red[0], red[1]), fmaxf(red[2], red[3]));
        const float scale = fmaxf(am, 1e-12f) / FP8MAX_;
        ws_scale[0] = scale;
        scale_out[0] = scale;
    }
}

__global__ __launch_bounds__(256) void k_quant_h(
    const unsigned int* __restrict__ normed_h2,
    const float* __restrict__ ws_scale, float* __restrict__ q_out)
{
    const float invs = 1.0f / ws_scale[0];
    const size_t n8 = NELEM / 8;
    const u32x4* __restrict__ src = reinterpret_cast<const u32x4*>(normed_h2);
    f32x4* __restrict__ dst = reinterpret_cast<f32x4*>(q_out);
    const size_t stride = (size_t)gridDim.x * blockDim.x;
    for (size_t i = (size_t)blockIdx.x * blockDim.x + threadIdx.x; i < n8;
         i += stride) {
        u32x4 u = src[i];
        float2 f0 = unpack_half2(u.x);
        float2 f1 = unpack_half2(u.y);
        float2 f2 = unpack_half2(u.z);
        float2 f3 = unpack_half2(u.w);
        f32x4 a, b;
        a.x = clip1(f0.x, invs);
        a.y = clip1(f0.y, invs);
        a.z = clip1(f1.x, invs);
        a.w = clip1(f1.y, invs);
        b.x = clip1(f2.x, invs);
        b.y = clip1(f2.y, invs);
        b.z = clip1(f3.x, invs);
        b.w = clip1(f3.y, invs);
        __builtin_nontemporal_store(a, &dst[i * 2]);
        __builtin_nontemporal_store(b, &dst[i * 2 + 1]);
    }
}

extern "C" void kernel_launch(void* const* d_in, const int* in_sizes, int n_in,
                              void* d_out, int out_size, void* d_ws, size_t ws_size,
                              hipStream_t stream) {
    const float* hs = (const float*)d_in[0];   // [TP, TOKENS, HIDDEN]
    // d_in[1] = residual: unused by the reference computation
    const float* w  = (const float*)d_in[2];   // [HIDDEN]
    float* out = (float*)d_out;                // [N] q values + [1] scale
    float* scale_out = out + NELEM;

    float* ws_scale = (float*)((char*)d_ws + WS_SCALE_OFF);
    float* bmax_arr = (float*)((char*)d_ws + WS_BMAX_OFF);

    void* args[] = {(void*)&hs, (void*)&w, (void*)&out, (void*)&scale_out,
                    (void*)&bmax_arr};
    hipError_t err = hipLaunchCooperativeKernel(
        (const void*)k_coop, dim3(1024), dim3(256), args, 0, stream);
    if (err != hipSuccess && ws_size >= WS_NEEDED_FB) {
        // proven three-kernel path (~152 us)
        unsigned int* normed_h2 = (unsigned int*)((char*)d_ws + WS_H16_OFF);
        k_norm_h<<<TOKENS_, 256, 0, stream>>>(hs, w, normed_h2, bmax_arr);
        k_amax_scale<<<1, 256, 0, stream>>>(bmax_arr, ws_scale, scale_out);
        k_quant_h<<<2048, 256, 0, stream>>>(normed_h2, ws_scale, out);
    }
}

// Round 7
// 150.079 us; speedup vs baseline: 2.2125x; 2.2125x over previous
//
#include <hip/hip_runtime.h>
#include <hip/hip_fp16.h>

#define TOKENS_ 8192
#define HIDDEN_ 4096
#define EPS_ 1e-6f
#define FP8MAX_ 448.0f

typedef float f32x4 __attribute__((ext_vector_type(4)));
typedef unsigned int u32x4 __attribute__((ext_vector_type(4)));

static constexpr size_t NELEM = (size_t)TOKENS_ * HIDDEN_;  // 33,554,432
// ws layout: [0..4) scale | [4K..4K+32K) bmax[8192] | [64K ...) fp16 buf
static constexpr size_t WS_SCALE_OFF = 0;
static constexpr size_t WS_BMAX_OFF = 4096;
static constexpr size_t WS_H16_OFF = 65536;
static constexpr size_t WS_NEEDED = WS_H16_OFF + NELEM * sizeof(unsigned short);

static __device__ inline unsigned int pack_half2(float a, float b) {
    __half2 h = __floats2half2_rn(a, b);
    return *reinterpret_cast<unsigned int*>(&h);
}
static __device__ inline float2 unpack_half2(unsigned int u) {
    return __half22float2(*reinterpret_cast<const __half2*>(&u));
}
static __device__ inline float clip1(float x, float invs) {
    return fminf(fmaxf(x * invs, -FP8MAX_), FP8MAX_);
}

// Pass 1: all-reduce + RMSNorm, one block per row. fp16 normed -> d_ws,
// per-block max -> bmax[row] (no atomics). hs read nontemporal (streaming,
// no reuse) to preserve L2/L3 capacity for the fp16 intermediate.
__global__ __launch_bounds__(256) void k_norm_h(
    const float* __restrict__ hs, const float* __restrict__ w,
    unsigned int* __restrict__ normed_h2, float* __restrict__ bmax_arr)
{
    const int row = blockIdx.x;
    const int tid = threadIdx.x;
    const size_t S4 = NELEM / 4;  // shard stride in f32x4 units
    const f32x4* __restrict__ base =
        reinterpret_cast<const f32x4*>(hs) + (size_t)row * (HIDDEN_ / 4);
    const f32x4* __restrict__ w4 = reinterpret_cast<const f32x4*>(w);

    f32x4 sv[4];
    float ss = 0.f;
#pragma unroll
    for (int j = 0; j < 4; ++j) {
        const size_t idx = (size_t)tid + j * 256;
        f32x4 a = __builtin_nontemporal_load(&base[idx]);
        f32x4 b = __builtin_nontemporal_load(&base[idx + S4]);
        f32x4 c = __builtin_nontemporal_load(&base[idx + 2 * S4]);
        f32x4 d = __builtin_nontemporal_load(&base[idx + 3 * S4]);
        f32x4 s = (a + b) + (c + d);
        sv[j] = s;
        ss += s.x * s.x + s.y * s.y + s.z * s.z + s.w * s.w;
    }

    __shared__ float red[4];
#pragma unroll
    for (int off = 32; off > 0; off >>= 1) ss += __shfl_down(ss, off, 64);
    const int wave = tid >> 6;
    if ((tid & 63) == 0) red[wave] = ss;
    __syncthreads();
    ss = red[0] + red[1] + red[2] + red[3];
    const float inv = rsqrtf(ss * (1.0f / HIDDEN_) + EPS_);

    uint2* __restrict__ out =
        reinterpret_cast<uint2*>(normed_h2) + (size_t)row * (HIDDEN_ / 4);
    float am = 0.f;
#pragma unroll
    for (int j = 0; j < 4; ++j) {
        const size_t idx = (size_t)tid + j * 256;
        f32x4 wv = w4[idx];
        f32x4 o = sv[j] * inv * wv;
        uint2 p;
        p.x = pack_half2(o.x, o.y);
        p.y = pack_half2(o.z, o.w);
        out[idx] = p;
        am = fmaxf(am, fmaxf(fmaxf(fabsf(o.x), fabsf(o.y)),
                             fmaxf(fabsf(o.z), fabsf(o.w))));
    }

    __shared__ float redm[4];
#pragma unroll
    for (int off = 32; off > 0; off >>= 1)
        am = fmaxf(am, __shfl_down(am, off, 64));
    if ((tid & 63) == 0) redm[wave] = am;
    __syncthreads();
    if (tid == 0)
        bmax_arr[row] = fmaxf(fmaxf(redm[0], redm[1]), fmaxf(redm[2], redm[3]));
}

// Pass 2 (fused): prologue — every block reduces bmax_arr[8192] (L2/L3
// resident after pass 1; kernel boundary guarantees visibility) to the
// global amax -> scale. Then fp16 normed -> scale+clip -> fp32 q with
// nontemporal stores. Block 0 writes the scale output.
__global__ __launch_bounds__(256) void k_quant_h2(
    const unsigned int* __restrict__ normed_h2,
    const float* __restrict__ bmax_arr, float* __restrict__ q_out,
    float* __restrict__ scale_out)
{
    const int tid = threadIdx.x;
    // --- amax reduction prologue ---
    const f32x4* __restrict__ b4 = reinterpret_cast<const f32x4*>(bmax_arr);
    float am = 0.f;
#pragma unroll
    for (int j = 0; j < 8; ++j) {  // 256 thr * 8 * 4 = 8192
        f32x4 v = b4[tid + j * 256];
        am = fmaxf(am, fmaxf(fmaxf(v.x, v.y), fmaxf(v.z, v.w)));
    }
    __shared__ float red[4];
#pragma unroll
    for (int off = 32; off > 0; off >>= 1)
        am = fmaxf(am, __shfl_down(am, off, 64));
    if ((tid & 63) == 0) red[tid >> 6] = am;
    __syncthreads();
    am = fmaxf(fmaxf(red[0], red[1]), fmaxf(red[2], red[3]));
    const float scale = fmaxf(am, 1e-12f) / FP8MAX_;
    const float invs = 1.0f / scale;
    if (blockIdx.x == 0 && tid == 0) scale_out[0] = scale;

    // --- quantization main loop ---
    const size_t n8 = NELEM / 8;
    const u32x4* __restrict__ src = reinterpret_cast<const u32x4*>(normed_h2);
    f32x4* __restrict__ dst = reinterpret_cast<f32x4*>(q_out);
    const size_t stride = (size_t)gridDim.x * blockDim.x;
    for (size_t i = (size_t)blockIdx.x * blockDim.x + tid; i < n8;
         i += stride) {
        u32x4 u = src[i];
        float2 f0 = unpack_half2(u.x);
        float2 f1 = unpack_half2(u.y);
        float2 f2 = unpack_half2(u.z);
        float2 f3 = unpack_half2(u.w);
        f32x4 a, b;
        a.x = clip1(f0.x, invs);
        a.y = clip1(f0.y, invs);
        a.z = clip1(f1.x, invs);
        a.w = clip1(f1.y, invs);
        b.x = clip1(f2.x, invs);
        b.y = clip1(f2.y, invs);
        b.z = clip1(f3.x, invs);
        b.w = clip1(f3.y, invs);
        __builtin_nontemporal_store(a, &dst[i * 2]);
        __builtin_nontemporal_store(b, &dst[i * 2 + 1]);
    }
}

// ---------------- fallback (ws too small): fp32 staged in d_out ------------

__global__ __launch_bounds__(256) void k_fused_norm_f(
    const float* __restrict__ hs, const float* __restrict__ w,
    float* __restrict__ normed, float* __restrict__ bmax_arr)
{
    const int row = blockIdx.x;
    const int tid = threadIdx.x;
    const size_t S4 = NELEM / 4;
    const f32x4* __restrict__ base =
        reinterpret_cast<const f32x4*>(hs) + (size_t)row * (HIDDEN_ / 4);
    const f32x4* __restrict__ w4 = reinterpret_cast<const f32x4*>(w);
    f32x4 sv[4];
    float ss = 0.f;
#pragma unroll
    for (int j = 0; j < 4; ++j) {
        const size_t idx = (size_t)tid + j * 256;
        f32x4 a = base[idx];
        f32x4 b = base[idx + S4];
        f32x4 c = base[idx + 2 * S4];
        f32x4 d = base[idx + 3 * S4];
        f32x4 s = (a + b) + (c + d);
        sv[j] = s;
        ss += s.x * s.x + s.y * s.y + s.z * s.z + s.w * s.w;
    }
    __shared__ float red[4];
#pragma unroll
    for (int off = 32; off > 0; off >>= 1) ss += __shfl_down(ss, off, 64);
    const int wave = tid >> 6;
    if ((tid & 63) == 0) red[wave] = ss;
    __syncthreads();
    ss = red[0] + red[1] + red[2] + red[3];
    const float inv = rsqrtf(ss * (1.0f / HIDDEN_) + EPS_);
    f32x4* __restrict__ out =
        reinterpret_cast<f32x4*>(normed) + (size_t)row * (HIDDEN_ / 4);
    float am = 0.f;
#pragma unroll
    for (int j = 0; j < 4; ++j) {
        const size_t idx = (size_t)tid + j * 256;
        f32x4 wv = w4[idx];
        f32x4 o = sv[j] * inv * wv;
        out[idx] = o;
        am = fmaxf(am, fmaxf(fmaxf(fabsf(o.x), fabsf(o.y)),
                             fmaxf(fabsf(o.z), fabsf(o.w))));
    }
    __shared__ float redm[4];
#pragma unroll
    for (int off = 32; off > 0; off >>= 1)
        am = fmaxf(am, __shfl_down(am, off, 64));
    if ((tid & 63) == 0) redm[wave] = am;
    __syncthreads();
    if (tid == 0)
        bmax_arr[row] = fmaxf(fmaxf(redm[0], redm[1]), fmaxf(redm[2], redm[3]));
}

__global__ __launch_bounds__(256) void k_quant_f2(
    float* __restrict__ data, const float* __restrict__ bmax_arr,
    float* __restrict__ scale_out)
{
    const int tid = threadIdx.x;
    const f32x4* __restrict__ b4 = reinterpret_cast<const f32x4*>(bmax_arr);
    float am = 0.f;
#pragma unroll
    for (int j = 0; j < 8; ++j) {
        f32x4 v = b4[tid + j * 256];
        am = fmaxf(am, fmaxf(fmaxf(v.x, v.y), fmaxf(v.z, v.w)));
    }
    __shared__ float red[4];
#pragma unroll
    for (int off = 32; off > 0; off >>= 1)
        am = fmaxf(am, __shfl_down(am, off, 64));
    if ((tid & 63) == 0) red[tid >> 6] = am;
    __syncthreads();
    am = fmaxf(fmaxf(red[0], red[1]), fmaxf(red[2], red[3]));
    const float scale = fmaxf(am, 1e-12f) / FP8MAX_;
    const float invs = 1.0f / scale;
    if (blockIdx.x == 0 && tid == 0) scale_out[0] = scale;

    const size_t n4 = NELEM / 4;
    f32x4* __restrict__ d4 = reinterpret_cast<f32x4*>(data);
    const size_t stride = (size_t)gridDim.x * blockDim.x;
    for (size_t i = (size_t)blockIdx.x * blockDim.x + tid; i < n4;
         i += stride) {
        f32x4 v = d4[i];
        v.x = clip1(v.x, invs);
        v.y = clip1(v.y, invs);
        v.z = clip1(v.z, invs);
        v.w = clip1(v.w, invs);
        d4[i] = v;
    }
}

extern "C" void kernel_launch(void* const* d_in, const int* in_sizes, int n_in,
                              void* d_out, int out_size, void* d_ws, size_t ws_size,
                              hipStream_t stream) {
    const float* hs = (const float*)d_in[0];   // [TP, TOKENS, HIDDEN]
    // d_in[1] = residual: unused by the reference computation
    const float* w  = (const float*)d_in[2];   // [HIDDEN]
    float* out = (float*)d_out;                // [N] q values + [1] scale
    float* scale_out = out + NELEM;
    float* bmax_arr = (float*)((char*)d_ws + WS_BMAX_OFF);

    if (ws_size >= WS_NEEDED) {
        unsigned int* normed_h2 = (unsigned int*)((char*)d_ws + WS_H16_OFF);
        k_norm_h<<<TOKENS_, 256, 0, stream>>>(hs, w, normed_h2, bmax_arr);
        k_quant_h2<<<2048, 256, 0, stream>>>(normed_h2, bmax_arr, out,
                                             scale_out);
    } else {
        k_fused_norm_f<<<TOKENS_, 256, 0, stream>>>(hs, w, out, bmax_arr);
        k_quant_f2<<<2048, 256, 0, stream>>>(out, bmax_arr, scale_out);
    }
}